// Round 5
// baseline (25.665 us; speedup 1.0000x reference)
//
#include <hip/hip_runtime.h>

// out[t,j,i,f] = (i==j ? 0 : tanh( (w0+w1)*node[t,i,f] - w1*node[t,j,f]
//                                  + w2*edge[t,i,j,f] + b ))
// T=8, N=128, F=128, float32.
//
// R4: identical to R3 except stores are regular (write-back, L2-allocating)
// instead of nontemporal. Wave owns 4(i) x 2(j) x F; in-register transpose
// via one __shfl_xor(.,32) per write step; reads and writes both 1KiB
// contiguous per wave instruction. No LDS, no barriers.

typedef float f32x4 __attribute__((ext_vector_type(4)));

__device__ __forceinline__ float fast_tanh(float x) {
    x = fminf(fmaxf(x, -9.0f), 9.0f);
    float t = __expf(2.0f * x);
    return (t - 1.0f) / (t + 1.0f);
}

__device__ __forceinline__ f32x4 shfl_xor32(f32x4 v) {
    f32x4 r;
    r.x = __shfl_xor(v.x, 32, 64);
    r.y = __shfl_xor(v.y, 32, 64);
    r.z = __shfl_xor(v.z, 32, 64);
    r.w = __shfl_xor(v.w, 32, 64);
    return r;
}

__global__ __launch_bounds__(256, 8)
void EdgeUpdateNetwork_44555990729422_kernel(
    const float* __restrict__ node,   // (T,N,F)
    const float* __restrict__ edge,   // (T,N,N,F)
    const float* __restrict__ w,      // (3,)
    const float* __restrict__ b,      // (1,)
    float* __restrict__ out)          // (T,N,N,F) swapped (1,2)
{
    const float w1  = w[1];
    const float w01 = w[0] + w1;
    const float w2  = w[2];
    const float bb  = b[0];

    // 4096 blocks: (t, ib:32, jb:16). Block tile = 4i x 8j x F.
    const int blk = blockIdx.x;
    const int jb  = blk & 15;
    const int ib  = (blk >> 4) & 31;
    const int t   = blk >> 9;
    const int i0  = ib << 2;
    const int j0  = jb << 3;

    const int tid  = threadIdx.x;
    const int wv   = tid >> 6;        // wave 0..3 -> j-pair within block
    const int lane = tid & 63;
    const int dq   = lane >> 5;       // 0/1
    const int f4   = lane & 31;

    const int jp = j0 + (wv << 1);    // wave's j-pair base
    const int jl = jp + dq;           // this thread's j (read phase)

    const f32x4* __restrict__ node4 = reinterpret_cast<const f32x4*>(node);
    const f32x4* __restrict__ edge4 = reinterpret_cast<const f32x4*>(edge);
    f32x4* __restrict__ out4        = reinterpret_cast<f32x4*>(out);

    // Hoisted: c = -w1 * node[t, jl, f] + b
    f32x4 nj = node4[(t * 128 + jl) * 32 + f4];
    f32x4 c  = (-w1) * nj + bb;

    // Read + compute: rv[r] = masked tanh for (i0+r, jl)
    f32x4 rv[4];
    #pragma unroll
    for (int r = 0; r < 4; ++r) {
        const int i = i0 + r;
        f32x4 ni = node4[(t * 128 + i) * 32 + f4];
        f32x4 e  = edge4[((t * 128 + i) * 128 + jl) * 32 + f4];
        f32x4 x  = w01 * ni + w2 * e + c;
        const float m = (i == jl) ? 0.0f : 1.0f;
        rv[r].x = m * fast_tanh(x.x);
        rv[r].y = m * fast_tanh(x.y);
        rv[r].z = m * fast_tanh(x.z);
        rv[r].w = m * fast_tanh(x.w);
    }

    // Write: step s covers i = i0+2s+dq for rows jp and jp+1.
    // dq=0 lacks (i0+2s, jp+1)   = partner's rv[2s]
    // dq=1 lacks (i0+2s+1, jp)   = partner's rv[2s+1]
    // -> one shfl_xor(32) per step: each half sends what the other needs.
    #pragma unroll
    for (int s = 0; s < 2; ++s) {
        const int iw = i0 + (s << 1) + dq;
        f32x4 send = (dq == 0) ? rv[2 * s + 1] : rv[2 * s];
        f32x4 recv = shfl_xor32(send);
        f32x4 v0 = (dq == 0) ? rv[2 * s] : recv;        // row jp
        f32x4 v1 = (dq == 0) ? recv : rv[2 * s + 1];    // row jp+1
        out4[((t * 128 + jp    ) * 128 + iw) * 32 + f4] = v0;
        out4[((t * 128 + jp + 1) * 128 + iw) * 32 + f4] = v1;
    }
}

extern "C" void kernel_launch(void* const* d_in, const int* in_sizes, int n_in,
                              void* d_out, int out_size, void* d_ws, size_t ws_size,
                              hipStream_t stream) {
    const float* node = (const float*)d_in[0];
    const float* edge = (const float*)d_in[1];
    const float* w    = (const float*)d_in[2];
    const float* b    = (const float*)d_in[3];
    float* out        = (float*)d_out;

    // T * (N/4) * (N/8) = 8*32*16 = 4096 blocks
    EdgeUpdateNetwork_44555990729422_kernel<<<4096, 256, 0, stream>>>(
        node, edge, w, b, out);
}

// Round 6
// 25.646 us; speedup vs baseline: 1.0007x; 1.0007x over previous
//
#include <hip/hip_runtime.h>

// out[t,j,i,f] = (i==j ? 0 : tanh( (w0+w1)*node[t,i,f] - w1*node[t,j,f]
//                                  + w2*edge[t,i,j,f] + b ))
// T=8, N=128, F=128, float32.
//
// R5: 8(i) x 8(j) x F tile per block (2048 blocks, 256 threads). Each wave
// owns 8i x 2j x F: 8 independent 1KiB edge loads in flight per thread
// (2x the MLP of R4), and both read and write sides see 4KiB contiguous
// runs per block step. In-register (i,j) transpose via one __shfl_xor(32)
// per write step. tanh uses raw v_exp + v_rcp (no IEEE div sequence).
// No LDS, no barriers.

typedef float f32x4 __attribute__((ext_vector_type(4)));

__device__ __forceinline__ float fast_tanh(float x) {
    x = fminf(fmaxf(x, -9.0f), 9.0f);
    // tanh(x) = (e^{2x}-1)/(e^{2x}+1);  e^{2x} = 2^(x*2*log2(e))
    float t = __builtin_amdgcn_exp2f(x * 2.8853900817779268f);
    return (t - 1.0f) * __builtin_amdgcn_rcpf(t + 1.0f);
}

__device__ __forceinline__ f32x4 shfl_xor32(f32x4 v) {
    f32x4 r;
    r.x = __shfl_xor(v.x, 32, 64);
    r.y = __shfl_xor(v.y, 32, 64);
    r.z = __shfl_xor(v.z, 32, 64);
    r.w = __shfl_xor(v.w, 32, 64);
    return r;
}

__global__ __launch_bounds__(256)
void EdgeUpdateNetwork_44555990729422_kernel(
    const float* __restrict__ node,   // (T,N,F)
    const float* __restrict__ edge,   // (T,N,N,F)
    const float* __restrict__ w,      // (3,)
    const float* __restrict__ b,      // (1,)
    float* __restrict__ out)          // (T,N,N,F) swapped (1,2)
{
    const float w1  = w[1];
    const float w01 = w[0] + w1;
    const float w2  = w[2];
    const float bb  = b[0];

    // 2048 blocks: (t, ib:16, jb:16). Block tile = 8i x 8j x F.
    const int blk = blockIdx.x;
    const int jb  = blk & 15;
    const int ib  = (blk >> 4) & 15;
    const int t   = blk >> 8;
    const int i0  = ib << 3;
    const int j0  = jb << 3;

    const int tid  = threadIdx.x;
    const int wv   = tid >> 6;        // wave 0..3 -> j-pair within block
    const int lane = tid & 63;
    const int dq   = lane >> 5;       // 0/1
    const int f4   = lane & 31;

    const int jp = j0 + (wv << 1);    // wave's j-pair base
    const int jl = jp + dq;           // this thread's j (read phase)

    const f32x4* __restrict__ node4 = reinterpret_cast<const f32x4*>(node);
    const f32x4* __restrict__ edge4 = reinterpret_cast<const f32x4*>(edge);
    f32x4* __restrict__ out4        = reinterpret_cast<f32x4*>(out);

    // Hoisted: c = -w1 * node[t, jl, f] + b
    f32x4 nj = node4[(t * 128 + jl) * 32 + f4];
    f32x4 c  = (-w1) * nj + bb;

    // Read + compute: rv[r] = masked tanh for (i0+r, jl), r = 0..7
    f32x4 rv[8];
    #pragma unroll
    for (int r = 0; r < 8; ++r) {
        const int i = i0 + r;
        f32x4 ni = node4[(t * 128 + i) * 32 + f4];
        f32x4 e  = edge4[((t * 128 + i) * 128 + jl) * 32 + f4];
        f32x4 x  = w01 * ni + w2 * e + c;
        const float m = (i == jl) ? 0.0f : 1.0f;
        rv[r].x = m * fast_tanh(x.x);
        rv[r].y = m * fast_tanh(x.y);
        rv[r].z = m * fast_tanh(x.z);
        rv[r].w = m * fast_tanh(x.w);
    }

    // Write: step s covers i = i0+2s+dq for rows jp and jp+1.
    // dq=0 lacks (i0+2s, jp+1)   = partner's rv[2s]
    // dq=1 lacks (i0+2s+1, jp)   = partner's rv[2s+1]
    // -> one shfl_xor(32) per step: each half sends what the other needs.
    #pragma unroll
    for (int s = 0; s < 4; ++s) {
        const int iw = i0 + (s << 1) + dq;
        f32x4 send = (dq == 0) ? rv[2 * s + 1] : rv[2 * s];
        f32x4 recv = shfl_xor32(send);
        f32x4 v0 = (dq == 0) ? rv[2 * s] : recv;        // row jp
        f32x4 v1 = (dq == 0) ? recv : rv[2 * s + 1];    // row jp+1
        out4[((t * 128 + jp    ) * 128 + iw) * 32 + f4] = v0;
        out4[((t * 128 + jp + 1) * 128 + iw) * 32 + f4] = v1;
    }
}

extern "C" void kernel_launch(void* const* d_in, const int* in_sizes, int n_in,
                              void* d_out, int out_size, void* d_ws, size_t ws_size,
                              hipStream_t stream) {
    const float* node = (const float*)d_in[0];
    const float* edge = (const float*)d_in[1];
    const float* w    = (const float*)d_in[2];
    const float* b    = (const float*)d_in[3];
    float* out        = (float*)d_out;

    // T * (N/8) * (N/8) = 8*16*16 = 2048 blocks
    EdgeUpdateNetwork_44555990729422_kernel<<<2048, 256, 0, stream>>>(
        node, edge, w, b, out);
}